// Round 6
// baseline (201.212 us; speedup 1.0000x reference)
//
#include <hip/hip_runtime.h>
#include <hip/hip_bf16.h>
#include <math.h>

#define BATCH 2
#define SEQ 2048
#define DMODEL 1024
#define NHEAD 16
#define DHEAD 64
#define MTOT (BATCH*SEQ)   // 4096

typedef __attribute__((ext_vector_type(8))) short bf16x8;
typedef __attribute__((ext_vector_type(4))) float f32x4;

static __device__ inline short f2bs(float x) {
    __hip_bfloat16 b = __float2bfloat16(x);
    return *reinterpret_cast<short*>(&b);
}

// ------------------------------------------------------------------
// fp32 -> bf16 conversion, weights only (4 x 1M elems).
// ------------------------------------------------------------------
struct ConvArgs {
    const float* src[4];
    unsigned short* dst[4];
};

__global__ __launch_bounds__(256)
void convert_bf16_kernel(ConvArgs a)
{
    const int r = blockIdx.x >> 9;          // 512 blocks per tensor
    const int b = blockIdx.x & 511;
    const float* s = a.src[r];
    unsigned short* d = a.dst[r];
    const int base = b * 2048 + threadIdx.x * 8;
    const float4 f0 = *reinterpret_cast<const float4*>(&s[base]);
    const float4 f1 = *reinterpret_cast<const float4*>(&s[base + 4]);
    bf16x8 o;
    o[0] = f2bs(f0.x); o[1] = f2bs(f0.y); o[2] = f2bs(f0.z); o[3] = f2bs(f0.w);
    o[4] = f2bs(f1.x); o[5] = f2bs(f1.y); o[6] = f2bs(f1.z); o[7] = f2bs(f1.w);
    *reinterpret_cast<bf16x8*>(&d[base]) = o;
}

// ------------------------------------------------------------------
// MFMA bf16 GEMM: out = X @ W^T + bias. 128x128 tile, BK=64, 4 waves,
// double-buffered swizzled LDS, reg-staged prefetch.
// XF32=1: X is fp32, converted to bf16 during staging (X-tiles L2-resident).
// SPLIT=1: write bf16 * scale scattered to [B,H,S,DK]; SPLIT=0: fp32 [M,N].
// ------------------------------------------------------------------
template<int SPLIT, int XF32>
__global__ __launch_bounds__(256)
void gemm_mfma_kernel(const void* __restrict__ Xp,
                      const __hip_bfloat16* __restrict__ W,
                      const float* __restrict__ bias,
                      void* __restrict__ outp, float scale)
{
    __shared__ short Xs[2][128 * 64];
    __shared__ short Wt[2][128 * 64];

    const int t    = threadIdx.x;
    const int lane = t & 63;
    const int w    = t >> 6;
    const int wm   = w >> 1, wn = w & 1;
    const int m_   = lane & 15, g = lane >> 4;

    const int m0 = blockIdx.y * 128;
    const int n0 = blockIdx.x * 128;

    const int sr  = t >> 1;
    const int sc0 = (t & 1) * 4;

    const short* Wg = (const short*)W;

    f32x4 acc[4][4] = {};
    bf16x8 xr[4], wr[4];

    // X load helper: elem index -> bf16x8 (converting if XF32)
    auto ldx = [&](size_t idx) -> bf16x8 {
        if (XF32) {
            const float* p = (const float*)Xp + idx;
            const float4 f0 = *reinterpret_cast<const float4*>(p);
            const float4 f1 = *reinterpret_cast<const float4*>(p + 4);
            bf16x8 o;
            o[0] = f2bs(f0.x); o[1] = f2bs(f0.y); o[2] = f2bs(f0.z); o[3] = f2bs(f0.w);
            o[4] = f2bs(f1.x); o[5] = f2bs(f1.y); o[6] = f2bs(f1.z); o[7] = f2bs(f1.w);
            return o;
        } else {
            return *reinterpret_cast<const bf16x8*>((const short*)Xp + idx);
        }
    };

    #pragma unroll
    for (int c = 0; c < 4; ++c) {
        xr[c] = ldx((size_t)(m0 + sr) * DMODEL + (sc0 + c) * 8);
        wr[c] = *reinterpret_cast<const bf16x8*>(&Wg[(size_t)(n0 + sr) * DMODEL + (sc0 + c) * 8]);
    }
    #pragma unroll
    for (int c = 0; c < 4; ++c) {
        const int byo = sr * 128 + (((sc0 + c) * 16) ^ ((sr & 7) << 4));
        *reinterpret_cast<bf16x8*>((char*)Xs[0] + byo) = xr[c];
        *reinterpret_cast<bf16x8*>((char*)Wt[0] + byo) = wr[c];
    }
    __syncthreads();

    for (int kt = 0; kt < DMODEL / 64; ++kt) {
        const int cur = kt & 1;
        const bool more = (kt < DMODEL / 64 - 1);

        if (more) {
            const int k0 = (kt + 1) * 64;
            #pragma unroll
            for (int c = 0; c < 4; ++c) {
                xr[c] = ldx((size_t)(m0 + sr) * DMODEL + k0 + (sc0 + c) * 8);
                wr[c] = *reinterpret_cast<const bf16x8*>(&Wg[(size_t)(n0 + sr) * DMODEL + k0 + (sc0 + c) * 8]);
            }
        }

        bf16x8 af[4][2], bfr[4][2];
        #pragma unroll
        for (int mt = 0; mt < 4; ++mt) {
            const int row = wm * 64 + mt * 16 + m_;
            #pragma unroll
            for (int kc = 0; kc < 2; ++kc)
                af[mt][kc] = *reinterpret_cast<const bf16x8*>(
                    (char*)Xs[cur] + row * 128 + ((kc * 64 + g * 16) ^ ((row & 7) << 4)));
        }
        #pragma unroll
        for (int nt = 0; nt < 4; ++nt) {
            const int row = wn * 64 + nt * 16 + m_;
            #pragma unroll
            for (int kc = 0; kc < 2; ++kc)
                bfr[nt][kc] = *reinterpret_cast<const bf16x8*>(
                    (char*)Wt[cur] + row * 128 + ((kc * 64 + g * 16) ^ ((row & 7) << 4)));
        }

        __builtin_amdgcn_s_setprio(1);
        #pragma unroll
        for (int mt = 0; mt < 4; ++mt)
            #pragma unroll
            for (int nt = 0; nt < 4; ++nt)
                #pragma unroll
                for (int kc = 0; kc < 2; ++kc)
                    acc[mt][nt] = __builtin_amdgcn_mfma_f32_16x16x32_bf16(
                        af[mt][kc], bfr[nt][kc], acc[mt][nt], 0, 0, 0);
        __builtin_amdgcn_s_setprio(0);

        if (more) {
            #pragma unroll
            for (int c = 0; c < 4; ++c) {
                const int byo = sr * 128 + (((sc0 + c) * 16) ^ ((sr & 7) << 4));
                *reinterpret_cast<bf16x8*>((char*)Xs[cur ^ 1] + byo) = xr[c];
                *reinterpret_cast<bf16x8*>((char*)Wt[cur ^ 1] + byo) = wr[c];
            }
        }
        __syncthreads();
    }

    float bv[4];
    #pragma unroll
    for (int nt = 0; nt < 4; ++nt) bv[nt] = bias[n0 + wn * 64 + nt * 16 + m_];

    #pragma unroll
    for (int mt = 0; mt < 4; ++mt) {
        #pragma unroll
        for (int r = 0; r < 4; ++r) {
            const int row = m0 + wm * 64 + mt * 16 + g * 4 + r;
            const int b = row >> 11;
            const int s = row & 2047;
            #pragma unroll
            for (int nt = 0; nt < 4; ++nt) {
                const int n = n0 + wn * 64 + nt * 16 + m_;
                const float c = (acc[mt][nt][r] + bv[nt]) * scale;
                if (SPLIT) {
                    const int h = n >> 6, dk = n & 63;
                    ((__hip_bfloat16*)outp)[(((size_t)(b * NHEAD + h)) * SEQ + s) * DHEAD + dk]
                        = __float2bfloat16(c);
                } else {
                    ((float*)outp)[(size_t)row * DMODEL + n] = c;
                }
            }
        }
    }
}

// ------------------------------------------------------------------
// Online-softmax helper (per-wave, 16 rows): reduction across 16 m-lanes.
// ------------------------------------------------------------------
static __device__ inline void online_sm(f32x4 s[4], float mrow[4], float lrow[4],
                                        f32x4 o[4])
{
    float pmax[4];
    #pragma unroll
    for (int r = 0; r < 4; ++r)
        pmax[r] = fmaxf(fmaxf(s[0][r], s[1][r]), fmaxf(s[2][r], s[3][r]));
    #pragma unroll
    for (int mk = 1; mk <= 8; mk <<= 1)
        #pragma unroll
        for (int r = 0; r < 4; ++r)
            pmax[r] = fmaxf(pmax[r], __shfl_xor(pmax[r], mk, 64));

    float scl[4];
    #pragma unroll
    for (int r = 0; r < 4; ++r) {
        const float mnew = fmaxf(mrow[r], pmax[r]);
        scl[r]  = __expf(mrow[r] - mnew);
        mrow[r] = mnew;
    }
    #pragma unroll
    for (int ct = 0; ct < 4; ++ct)
        #pragma unroll
        for (int r = 0; r < 4; ++r)
            s[ct][r] = __expf(s[ct][r] - mrow[r]);

    float psum[4];
    #pragma unroll
    for (int r = 0; r < 4; ++r)
        psum[r] = (s[0][r] + s[1][r]) + (s[2][r] + s[3][r]);
    #pragma unroll
    for (int mk = 1; mk <= 8; mk <<= 1)
        #pragma unroll
        for (int r = 0; r < 4; ++r)
            psum[r] += __shfl_xor(psum[r], mk, 64);
    #pragma unroll
    for (int r = 0; r < 4; ++r)
        lrow[r] = lrow[r] * scl[r] + psum[r];

    #pragma unroll
    for (int dt = 0; dt < 4; ++dt)
        #pragma unroll
        for (int r = 0; r < 4; ++r)
            o[dt][r] *= scl[r];
}

// ------------------------------------------------------------------
// Paired-tile MFMA causal flash attention, 8 waves / 512 threads.
// Block = (b,h,pr): waves 0-3 own q-tile qtA=pr, waves 4-7 own qtB=31-pr.
// Per-iteration active work constant across blocks: (qtA+1)*2+(qtB-qtA)=33.
// K/V staged once per kt by all 512 threads, shared by all 8 waves.
// ------------------------------------------------------------------
__global__ __launch_bounds__(512, 4)
void attn_mfma_kernel(const __hip_bfloat16* __restrict__ Q,
                      const __hip_bfloat16* __restrict__ K,
                      const __hip_bfloat16* __restrict__ V,
                      __hip_bfloat16* __restrict__ ctx)
{
    __shared__ short Ks[64 * 64];       // K tile [kv][d], swizzled 128B rows
    __shared__ short Vts[64 * 64];      // V^T tile [d][kv], swizzled
    __shared__ short Ps[8 * 16 * 72];   // per-wave P tiles

    const int t    = threadIdx.x;
    const int lane = t & 63;
    const int w    = t >> 6;        // 0..7
    const int wq   = w & 3;         // wave-within-side
    const int side = w >> 2;        // 0 = tile A, 1 = tile B
    const int m    = lane & 15;
    const int g    = lane >> 4;

    // XCD-chunked swizzle: 512 blocks = 8 XCDs x 64
    const int bid = blockIdx.x;
    const int swz = (bid & 7) * 64 + (bid >> 3);
    const int bh  = swz >> 4;       // 0..31
    const int pr  = swz & 15;       // 0..15
    const int qtA = pr, qtB = 31 - pr;
    const int myqt = side ? qtB : qtA;
    const int q0   = myqt * 64;

    const __hip_bfloat16* Qb = Q + (size_t)bh * SEQ * DHEAD;
    const __hip_bfloat16* Kb = K + (size_t)bh * SEQ * DHEAD;
    const __hip_bfloat16* Vb = V + (size_t)bh * SEQ * DHEAD;

    bf16x8 qf[2];
    #pragma unroll
    for (int c = 0; c < 2; ++c)
        qf[c] = *reinterpret_cast<const bf16x8*>(
            &Qb[(size_t)(q0 + 16 * wq + m) * DHEAD + c * 32 + 8 * g]);

    f32x4 o[4] = {};
    float mr[4], lr[4];
    #pragma unroll
    for (int r = 0; r < 4; ++r) { mr[r] = -INFINITY; lr[r] = 0.0f; }

    short* Pw = Ps + w * 16 * 72;

    for (int kt = 0; kt <= qtB; ++kt) {
        const int k0 = kt * 64;

        // ---- stage K + V^T (512 threads, 8 elems each per tensor) ----
        {
            const int krow = t >> 3;        // 0..63
            const int kch  = t & 7;         // 16B chunk
            const bf16x8 kv = *reinterpret_cast<const bf16x8*>(
                &Kb[(size_t)(k0 + krow) * DHEAD + kch * 8]);
            *reinterpret_cast<bf16x8*>((char*)Ks +
                (((krow * 128) + kch * 16) ^ ((krow & 7) << 4))) = kv;

            const int vk = t & 63;
            const int d0 = (t >> 6) * 8;    // 0..56
            const bf16x8 vv = *reinterpret_cast<const bf16x8*>(
                &Vb[(size_t)(k0 + vk) * DHEAD + d0]);
            #pragma unroll
            for (int j = 0; j < 8; ++j) {
                const int d = d0 + j;
                *reinterpret_cast<short*>((char*)Vts +
                    (((d * 128) + vk * 2) ^ ((d & 7) << 4))) = vv[j];
            }
        }
        __syncthreads();

        if (kt <= myqt) {
            // ---- QK^T ----
            f32x4 s[4] = {};
            __builtin_amdgcn_s_setprio(1);
            #pragma unroll
            for (int ct = 0; ct < 4; ++ct) {
                const int krow = ct * 16 + m;
                #pragma unroll
                for (int c = 0; c < 2; ++c) {
                    const bf16x8 kf = *reinterpret_cast<const bf16x8*>((char*)Ks +
                        (((krow * 128) + c * 64 + 16 * g) ^ ((krow & 7) << 4)));
                    s[ct] = __builtin_amdgcn_mfma_f32_16x16x32_bf16(qf[c], kf, s[ct], 0, 0, 0);
                }
            }
            __builtin_amdgcn_s_setprio(0);

            // ---- causal mask on diagonal tile ----
            if (kt == myqt) {
                #pragma unroll
                for (int ct = 0; ct < 4; ++ct) {
                    const int kp = ct * 16 + m;
                    #pragma unroll
                    for (int r = 0; r < 4; ++r)
                        if (kp > 16 * wq + 4 * g + r) s[ct][r] = -INFINITY;
                }
            }

            online_sm(s, mr, lr, o);

            // ---- P -> bf16 LDS (per-wave region, no barrier needed) ----
            #pragma unroll
            for (int ct = 0; ct < 4; ++ct)
                #pragma unroll
                for (int r = 0; r < 4; ++r)
                    Pw[(4 * g + r) * 72 + ct * 16 + m] = f2bs(s[ct][r]);

            bf16x8 pf[2];
            #pragma unroll
            for (int c = 0; c < 2; ++c)
                pf[c] = *reinterpret_cast<const bf16x8*>(&Pw[m * 72 + c * 32 + 8 * g]);

            // ---- O += P V ----
            __builtin_amdgcn_s_setprio(1);
            #pragma unroll
            for (int dt = 0; dt < 4; ++dt) {
                const int vrow = dt * 16 + m;
                #pragma unroll
                for (int c = 0; c < 2; ++c) {
                    const bf16x8 vf = *reinterpret_cast<const bf16x8*>((char*)Vts +
                        (((vrow * 128) + c * 64 + 16 * g) ^ ((vrow & 7) << 4)));
                    o[dt] = __builtin_amdgcn_mfma_f32_16x16x32_bf16(pf[c], vf, o[dt], 0, 0, 0);
                }
            }
            __builtin_amdgcn_s_setprio(0);
        }
        __syncthreads();
    }

    // ---- epilogue ----
    const int b = bh >> 4;
    const int h = bh & 15;
    #pragma unroll
    for (int r = 0; r < 4; ++r) {
        const float inv = 1.0f / lr[r];
        const int row = q0 + 16 * wq + 4 * g + r;
        __hip_bfloat16* dst = &ctx[((size_t)(b * SEQ) + row) * DMODEL + h * DHEAD];
        #pragma unroll
        for (int dt = 0; dt < 4; ++dt)
            dst[dt * 16 + m] = __float2bfloat16(o[dt][r] * inv);
    }
}

// ------------------------------------------------------------------
extern "C" void kernel_launch(void* const* d_in, const int* in_sizes, int n_in,
                              void* d_out, int out_size, void* d_ws, size_t ws_size,
                              hipStream_t stream)
{
    const float* query = (const float*)d_in[0];
    const float* key   = (const float*)d_in[1];
    const float* value = (const float*)d_in[2];
    // d_in[3] = mask: fixed causal tril — implemented directly
    const float* Wq = (const float*)d_in[4];
    const float* bq = (const float*)d_in[5];
    const float* Wk = (const float*)d_in[6];
    const float* bk = (const float*)d_in[7];
    const float* Wv = (const float*)d_in[8];
    const float* bv = (const float*)d_in[9];
    const float* Wo = (const float*)d_in[10];
    const float* bo = (const float*)d_in[11];
    float* out = (float*)d_out;

    // ws layout: wqb/wkb/wvb/wob bf16 (2MB each) at 0..8MB;
    //            qb 8..16MB, kb 16..24MB, vb 24..32MB ([B,H,S,DK] bf16);
    //            ctx 32..40MB ([B,S,D] bf16)
    char* ws = (char*)d_ws;
    const size_t MB = 1024 * 1024;
    unsigned short* wqb = (unsigned short*)(ws + 0 * MB);
    unsigned short* wkb = (unsigned short*)(ws + 2 * MB);
    unsigned short* wvb = (unsigned short*)(ws + 4 * MB);
    unsigned short* wob = (unsigned short*)(ws + 6 * MB);
    __hip_bfloat16* qb  = (__hip_bfloat16*)(ws + 8 * MB);
    __hip_bfloat16* kb  = (__hip_bfloat16*)(ws + 16 * MB);
    __hip_bfloat16* vb  = (__hip_bfloat16*)(ws + 24 * MB);
    __hip_bfloat16* ctx = (__hip_bfloat16*)(ws + 32 * MB);

    ConvArgs ca;
    ca.src[0] = Wq; ca.dst[0] = wqb;
    ca.src[1] = Wk; ca.dst[1] = wkb;
    ca.src[2] = Wv; ca.dst[2] = wvb;
    ca.src[3] = Wo; ca.dst[3] = wob;
    convert_bf16_kernel<<<dim3(2048), dim3(256), 0, stream>>>(ca);

    const dim3 gg(DMODEL / 128, MTOT / 128);   // (8, 32)
    const dim3 bb(256);
    gemm_mfma_kernel<1, 1><<<gg, bb, 0, stream>>>(
        query, (const __hip_bfloat16*)wqb, bq, qb, 0.125f);
    gemm_mfma_kernel<1, 1><<<gg, bb, 0, stream>>>(
        key, (const __hip_bfloat16*)wkb, bk, kb, 1.0f);
    gemm_mfma_kernel<1, 1><<<gg, bb, 0, stream>>>(
        value, (const __hip_bfloat16*)wvb, bv, vb, 1.0f);
    attn_mfma_kernel<<<dim3(512), dim3(512), 0, stream>>>(qb, kb, vb, ctx);
    gemm_mfma_kernel<0, 0><<<gg, bb, 0, stream>>>(
        ctx, (const __hip_bfloat16*)wob, bo, out, 1.0f);
}

// Round 7
// 133.504 us; speedup vs baseline: 1.5072x; 1.5072x over previous
//
#include <hip/hip_runtime.h>
#include <hip/hip_bf16.h>
#include <math.h>

#define BATCH 2
#define SEQ 2048
#define DMODEL 1024
#define NHEAD 16
#define DHEAD 64
#define MTOT (BATCH*SEQ)   // 4096

typedef __attribute__((ext_vector_type(8))) short bf16x8;
typedef __attribute__((ext_vector_type(4))) short short4v;
typedef __attribute__((ext_vector_type(4))) float f32x4;

static __device__ inline short f2bs(float x) {
    __hip_bfloat16 b = __float2bfloat16(x);
    return *reinterpret_cast<short*>(&b);
}

// ------------------------------------------------------------------
// Batched fp32 -> bf16 conversion over 7 tensors (3 inputs, 4 weights).
// ------------------------------------------------------------------
struct ConvArgs {
    const float* src[7];
    unsigned short* dst[7];
    int nblk[7];
};

__global__ __launch_bounds__(256)
void convert_bf16_kernel(ConvArgs a)
{
    int b = blockIdx.x;
    int r = 0;
    while (b >= a.nblk[r]) { b -= a.nblk[r]; ++r; }
    const float* s = a.src[r];
    unsigned short* d = a.dst[r];
    const int base = b * 2048 + threadIdx.x * 8;
    const float4 f0 = *reinterpret_cast<const float4*>(&s[base]);
    const float4 f1 = *reinterpret_cast<const float4*>(&s[base + 4]);
    bf16x8 o;
    o[0] = f2bs(f0.x); o[1] = f2bs(f0.y); o[2] = f2bs(f0.z); o[3] = f2bs(f0.w);
    o[4] = f2bs(f1.x); o[5] = f2bs(f1.y); o[6] = f2bs(f1.z); o[7] = f2bs(f1.w);
    *reinterpret_cast<bf16x8*>(&d[base]) = o;
}

// ------------------------------------------------------------------
// MFMA bf16 GEMM core: out = X[M,1024] @ W[1024,1024]^T + bias.
// 128x128 tile, BK=64, 4 waves, double-buffered swizzled LDS,
// reg-staged prefetch. SPLIT=1: bf16*scale -> [B,H,S,DK]; 0: fp32 [M,N].
// ------------------------------------------------------------------
template<int SPLIT>
static __device__ __forceinline__
void gemm_core(const short* __restrict__ Xg, const short* __restrict__ Wg,
               const float* __restrict__ bias, void* __restrict__ outp,
               float scale, int m0, int n0)
{
    __shared__ short Xs[2][128 * 64];
    __shared__ short Wt[2][128 * 64];

    const int t    = threadIdx.x;
    const int lane = t & 63;
    const int w    = t >> 6;
    const int wm   = w >> 1, wn = w & 1;
    const int m_   = lane & 15, g = lane >> 4;

    const int sr  = t >> 1;
    const int sc0 = (t & 1) * 4;

    f32x4 acc[4][4] = {};
    bf16x8 xr[4], wr[4];

    #pragma unroll
    for (int c = 0; c < 4; ++c) {
        xr[c] = *reinterpret_cast<const bf16x8*>(&Xg[(size_t)(m0 + sr) * DMODEL + (sc0 + c) * 8]);
        wr[c] = *reinterpret_cast<const bf16x8*>(&Wg[(size_t)(n0 + sr) * DMODEL + (sc0 + c) * 8]);
    }
    #pragma unroll
    for (int c = 0; c < 4; ++c) {
        const int byo = sr * 128 + (((sc0 + c) * 16) ^ ((sr & 7) << 4));
        *reinterpret_cast<bf16x8*>((char*)Xs[0] + byo) = xr[c];
        *reinterpret_cast<bf16x8*>((char*)Wt[0] + byo) = wr[c];
    }
    __syncthreads();

    for (int kt = 0; kt < DMODEL / 64; ++kt) {
        const int cur = kt & 1;
        const bool more = (kt < DMODEL / 64 - 1);

        if (more) {
            const int k0 = (kt + 1) * 64;
            #pragma unroll
            for (int c = 0; c < 4; ++c) {
                xr[c] = *reinterpret_cast<const bf16x8*>(&Xg[(size_t)(m0 + sr) * DMODEL + k0 + (sc0 + c) * 8]);
                wr[c] = *reinterpret_cast<const bf16x8*>(&Wg[(size_t)(n0 + sr) * DMODEL + k0 + (sc0 + c) * 8]);
            }
        }

        bf16x8 af[4][2], bfr[4][2];
        #pragma unroll
        for (int mt = 0; mt < 4; ++mt) {
            const int row = wm * 64 + mt * 16 + m_;
            #pragma unroll
            for (int kc = 0; kc < 2; ++kc)
                af[mt][kc] = *reinterpret_cast<const bf16x8*>(
                    (char*)Xs[cur] + row * 128 + ((kc * 64 + g * 16) ^ ((row & 7) << 4)));
        }
        #pragma unroll
        for (int nt = 0; nt < 4; ++nt) {
            const int row = wn * 64 + nt * 16 + m_;
            #pragma unroll
            for (int kc = 0; kc < 2; ++kc)
                bfr[nt][kc] = *reinterpret_cast<const bf16x8*>(
                    (char*)Wt[cur] + row * 128 + ((kc * 64 + g * 16) ^ ((row & 7) << 4)));
        }

        __builtin_amdgcn_s_setprio(1);
        #pragma unroll
        for (int mt = 0; mt < 4; ++mt)
            #pragma unroll
            for (int nt = 0; nt < 4; ++nt)
                #pragma unroll
                for (int kc = 0; kc < 2; ++kc)
                    acc[mt][nt] = __builtin_amdgcn_mfma_f32_16x16x32_bf16(
                        af[mt][kc], bfr[nt][kc], acc[mt][nt], 0, 0, 0);
        __builtin_amdgcn_s_setprio(0);

        if (more) {
            #pragma unroll
            for (int c = 0; c < 4; ++c) {
                const int byo = sr * 128 + (((sc0 + c) * 16) ^ ((sr & 7) << 4));
                *reinterpret_cast<bf16x8*>((char*)Xs[cur ^ 1] + byo) = xr[c];
                *reinterpret_cast<bf16x8*>((char*)Wt[cur ^ 1] + byo) = wr[c];
            }
        }
        __syncthreads();
    }

    float bv[4];
    #pragma unroll
    for (int nt = 0; nt < 4; ++nt) bv[nt] = bias[n0 + wn * 64 + nt * 16 + m_];

    #pragma unroll
    for (int mt = 0; mt < 4; ++mt) {
        #pragma unroll
        for (int r = 0; r < 4; ++r) {
            const int row = m0 + wm * 64 + mt * 16 + g * 4 + r;
            const int b = row >> 11;
            const int s = row & 2047;
            #pragma unroll
            for (int nt = 0; nt < 4; ++nt) {
                const int n = n0 + wn * 64 + nt * 16 + m_;
                const float c = (acc[mt][nt][r] + bv[nt]) * scale;
                if (SPLIT) {
                    const int h = n >> 6, dk = n & 63;
                    ((__hip_bfloat16*)outp)[(((size_t)(b * NHEAD + h)) * SEQ + s) * DHEAD + dk]
                        = __float2bfloat16(c);
                } else {
                    ((float*)outp)[(size_t)row * DMODEL + n] = c;
                }
            }
        }
    }
}

// Fused Q/K/V projection: grid 768 = 3 x 256 tiles.
struct TrioArgs {
    const short* X[3];
    const short* W[3];
    const float* bias[3];
    __hip_bfloat16* out[3];
    float scale[3];
};

__global__ __launch_bounds__(256)
void gemm_qkv_kernel(TrioArgs a)
{
    const int which = blockIdx.x >> 8;       // 0..2
    const int tile  = blockIdx.x & 255;      // 0..255
    const int n0 = (tile & 7) * 128;
    const int m0 = (tile >> 3) * 128;
    gemm_core<1>(a.X[which], a.W[which], a.bias[which], a.out[which],
                 a.scale[which], m0, n0);
}

__global__ __launch_bounds__(256)
void gemm_out_kernel(const short* __restrict__ X, const short* __restrict__ W,
                     const float* __restrict__ bias, float* __restrict__ out)
{
    gemm_core<0>(X, W, bias, out, 1.0f, blockIdx.y * 128, blockIdx.x * 128);
}

// ------------------------------------------------------------------
// Paired-tile MFMA causal flash attention, 8 waves / 512 threads.
// SWAPPED operands: S^T = mfma(K,Q), O^T = mfma(V^T,P^T).
// Lane (m = lane&15, g = lane>>4) owns q-row m (of its wave's 16) and
// k-positions {ct*16 + 4g + r}. Softmax: local 16-value reduce + 2 shfl.
// ------------------------------------------------------------------
__global__ __launch_bounds__(512, 4)
void attn_mfma_kernel(const __hip_bfloat16* __restrict__ Q,
                      const __hip_bfloat16* __restrict__ K,
                      const __hip_bfloat16* __restrict__ V,
                      __hip_bfloat16* __restrict__ ctx)
{
    __shared__ short Ks[64 * 64];       // K tile [kv][d], swizzled 128B rows
    __shared__ short Vts[64 * 64];      // V^T tile [d][kv], swizzled
    __shared__ short Ps[8 * 16 * 72];   // per-wave P [q][k], stride 72

    const int t    = threadIdx.x;
    const int lane = t & 63;
    const int w    = t >> 6;        // 0..7
    const int wq   = w & 3;         // wave-within-side
    const int side = w >> 2;        // 0 = tile A, 1 = tile B
    const int m    = lane & 15;
    const int g    = lane >> 4;

    // XCD-chunked swizzle: 512 blocks = 8 XCDs x 64
    const int bid = blockIdx.x;
    const int swz = (bid & 7) * 64 + (bid >> 3);
    const int bh  = swz >> 4;       // 0..31
    const int pr  = swz & 15;       // 0..15
    const int qtA = pr, qtB = 31 - pr;
    const int myqt = side ? qtB : qtA;
    const int q0   = myqt * 64;

    const __hip_bfloat16* Qb = Q + (size_t)bh * SEQ * DHEAD;
    const __hip_bfloat16* Kb = K + (size_t)bh * SEQ * DHEAD;
    const __hip_bfloat16* Vb = V + (size_t)bh * SEQ * DHEAD;

    // Q fragments (B-operand of S^T): lane holds Q[q0+16wq+m][c*32+8g .. +7]
    bf16x8 qf[2];
    #pragma unroll
    for (int c = 0; c < 2; ++c)
        qf[c] = *reinterpret_cast<const bf16x8*>(
            &Qb[(size_t)(q0 + 16 * wq + m) * DHEAD + c * 32 + 8 * g]);

    f32x4 o[4] = {};       // O^T: o[dt][r] = O[q=m][d=dt*16+4g+r]
    float mr = -INFINITY, lr = 0.0f;

    short* Pw = Ps + w * 16 * 72;

    for (int kt = 0; kt <= qtB; ++kt) {
        const int k0 = kt * 64;

        // ---- stage K + V^T (512 threads) ----
        {
            const int krow = t >> 3;        // 0..63
            const int kch  = t & 7;         // 16B chunk
            const bf16x8 kv = *reinterpret_cast<const bf16x8*>(
                &Kb[(size_t)(k0 + krow) * DHEAD + kch * 8]);
            *reinterpret_cast<bf16x8*>((char*)Ks +
                (((krow * 128) + kch * 16) ^ ((krow & 7) << 4))) = kv;

            const int vk = t & 63;
            const int d0 = (t >> 6) * 8;    // 0..56
            const bf16x8 vv = *reinterpret_cast<const bf16x8*>(
                &Vb[(size_t)(k0 + vk) * DHEAD + d0]);
            #pragma unroll
            for (int j = 0; j < 8; ++j) {
                const int d = d0 + j;
                *reinterpret_cast<short*>((char*)Vts +
                    (((d * 128) + vk * 2) ^ ((d & 7) << 4))) = vv[j];
            }
        }
        __syncthreads();

        if (kt <= myqt) {
            // ---- S^T = K Q^T : s[ct][r] = S[q=m][k=ct*16+4g+r] ----
            f32x4 s[4] = {};
            __builtin_amdgcn_s_setprio(1);
            #pragma unroll
            for (int ct = 0; ct < 4; ++ct) {
                const int krow = ct * 16 + m;
                #pragma unroll
                for (int c = 0; c < 2; ++c) {
                    const bf16x8 kf = *reinterpret_cast<const bf16x8*>((char*)Ks +
                        (((krow * 128) + c * 64 + 16 * g) ^ ((krow & 7) << 4)));
                    s[ct] = __builtin_amdgcn_mfma_f32_16x16x32_bf16(kf, qf[c], s[ct], 0, 0, 0);
                }
            }
            __builtin_amdgcn_s_setprio(0);

            // ---- causal mask (diagonal tile): k-local kp vs q-local 16wq+m ----
            if (kt == myqt) {
                const int qr = 16 * wq + m;
                #pragma unroll
                for (int ct = 0; ct < 4; ++ct)
                    #pragma unroll
                    for (int r = 0; r < 4; ++r)
                        if (ct * 16 + 4 * g + r > qr) s[ct][r] = -INFINITY;
            }

            // ---- online softmax: 16 local values + 2 shfl rounds ----
            float pmax = -INFINITY;
            #pragma unroll
            for (int ct = 0; ct < 4; ++ct) {
                const float a = fmaxf(fmaxf(s[ct][0], s[ct][1]),
                                      fmaxf(s[ct][2], s[ct][3]));
                pmax = fmaxf(pmax, a);
            }
            pmax = fmaxf(pmax, __shfl_xor(pmax, 16, 64));
            pmax = fmaxf(pmax, __shfl_xor(pmax, 32, 64));

            const float mnew = fmaxf(mr, pmax);
            const float scl  = __expf(mr - mnew);   // first tile: exp(-inf)=0
            mr = mnew;

            float psum = 0.0f;
            #pragma unroll
            for (int ct = 0; ct < 4; ++ct) {
                #pragma unroll
                for (int r = 0; r < 4; ++r) {
                    s[ct][r] = __expf(s[ct][r] - mnew);
                    psum += s[ct][r];
                }
            }
            psum += __shfl_xor(psum, 16, 64);
            psum += __shfl_xor(psum, 32, 64);
            lr = lr * scl + psum;

            #pragma unroll
            for (int dt = 0; dt < 4; ++dt)
                #pragma unroll
                for (int r = 0; r < 4; ++r)
                    o[dt][r] *= scl;

            // ---- P -> bf16 LDS: lane writes 4 consecutive k as one b64 ----
            #pragma unroll
            for (int ct = 0; ct < 4; ++ct) {
                short4v p4;
                p4[0] = f2bs(s[ct][0]); p4[1] = f2bs(s[ct][1]);
                p4[2] = f2bs(s[ct][2]); p4[3] = f2bs(s[ct][3]);
                *reinterpret_cast<short4v*>(&Pw[m * 72 + ct * 16 + 4 * g]) = p4;
            }

            // ---- pf (B-operand of O^T): P[q=m][c*32+8g .. +7] ----
            bf16x8 pf[2];
            #pragma unroll
            for (int c = 0; c < 2; ++c)
                pf[c] = *reinterpret_cast<const bf16x8*>(&Pw[m * 72 + c * 32 + 8 * g]);

            // ---- O^T += V^T P^T ----
            __builtin_amdgcn_s_setprio(1);
            #pragma unroll
            for (int dt = 0; dt < 4; ++dt) {
                const int vrow = dt * 16 + m;
                #pragma unroll
                for (int c = 0; c < 2; ++c) {
                    const bf16x8 vf = *reinterpret_cast<const bf16x8*>((char*)Vts +
                        (((vrow * 128) + c * 64 + 16 * g) ^ ((vrow & 7) << 4)));
                    o[dt] = __builtin_amdgcn_mfma_f32_16x16x32_bf16(vf, pf[c], o[dt], 0, 0, 0);
                }
            }
            __builtin_amdgcn_s_setprio(0);
        }
        __syncthreads();
    }

    // ---- epilogue: lane owns q-row m; 8B packed stores ----
    const int b = bh >> 4;
    const int h = bh & 15;
    const float inv = 1.0f / lr;
    const int row = q0 + 16 * wq + m;
    short* dst = (short*)&ctx[((size_t)(b * SEQ) + row) * DMODEL + h * DHEAD];
    #pragma unroll
    for (int dt = 0; dt < 4; ++dt) {
        short4v p4;
        p4[0] = f2bs(o[dt][0] * inv); p4[1] = f2bs(o[dt][1] * inv);
        p4[2] = f2bs(o[dt][2] * inv); p4[3] = f2bs(o[dt][3] * inv);
        *reinterpret_cast<short4v*>(dst + dt * 16 + 4 * g) = p4;
    }
}

// ------------------------------------------------------------------
extern "C" void kernel_launch(void* const* d_in, const int* in_sizes, int n_in,
                              void* d_out, int out_size, void* d_ws, size_t ws_size,
                              hipStream_t stream)
{
    const float* query = (const float*)d_in[0];
    const float* key   = (const float*)d_in[1];
    const float* value = (const float*)d_in[2];
    // d_in[3] = mask: fixed causal tril — implemented directly
    const float* Wq = (const float*)d_in[4];
    const float* bq = (const float*)d_in[5];
    const float* Wk = (const float*)d_in[6];
    const float* bk = (const float*)d_in[7];
    const float* Wv = (const float*)d_in[8];
    const float* bv = (const float*)d_in[9];
    const float* Wo = (const float*)d_in[10];
    const float* bo = (const float*)d_in[11];
    float* out = (float*)d_out;

    // ws layout: xq 0..8M, xk 8..16M, xv 16..24M (bf16 inputs);
    //            wqb 24..26M, wkb 26..28M, wvb 28..30M, wob 30..32M;
    //            qb 32..40M, kb 40..48M, vb 48..56M ([B,H,S,DK] bf16);
    //            ctx 56..64M ([B,S,D] bf16)
    char* ws = (char*)d_ws;
    const size_t MB = 1024 * 1024;
    unsigned short* xq  = (unsigned short*)(ws + 0 * MB);
    unsigned short* xk  = (unsigned short*)(ws + 8 * MB);
    unsigned short* xv  = (unsigned short*)(ws + 16 * MB);
    unsigned short* wqb = (unsigned short*)(ws + 24 * MB);
    unsigned short* wkb = (unsigned short*)(ws + 26 * MB);
    unsigned short* wvb = (unsigned short*)(ws + 28 * MB);
    unsigned short* wob = (unsigned short*)(ws + 30 * MB);
    __hip_bfloat16* qb  = (__hip_bfloat16*)(ws + 32 * MB);
    __hip_bfloat16* kb  = (__hip_bfloat16*)(ws + 40 * MB);
    __hip_bfloat16* vb  = (__hip_bfloat16*)(ws + 48 * MB);
    __hip_bfloat16* ctx = (__hip_bfloat16*)(ws + 56 * MB);

    ConvArgs ca;
    ca.src[0] = query; ca.dst[0] = xq;  ca.nblk[0] = 2048;
    ca.src[1] = key;   ca.dst[1] = xk;  ca.nblk[1] = 2048;
    ca.src[2] = value; ca.dst[2] = xv;  ca.nblk[2] = 2048;
    ca.src[3] = Wq;    ca.dst[3] = wqb; ca.nblk[3] = 512;
    ca.src[4] = Wk;    ca.dst[4] = wkb; ca.nblk[4] = 512;
    ca.src[5] = Wv;    ca.dst[5] = wvb; ca.nblk[5] = 512;
    ca.src[6] = Wo;    ca.dst[6] = wob; ca.nblk[6] = 512;
    convert_bf16_kernel<<<dim3(8192), dim3(256), 0, stream>>>(ca);

    TrioArgs ta;
    ta.X[0] = (const short*)xq; ta.W[0] = (const short*)wqb; ta.bias[0] = bq;
    ta.out[0] = qb; ta.scale[0] = 0.125f;
    ta.X[1] = (const short*)xk; ta.W[1] = (const short*)wkb; ta.bias[1] = bk;
    ta.out[1] = kb; ta.scale[1] = 1.0f;
    ta.X[2] = (const short*)xv; ta.W[2] = (const short*)wvb; ta.bias[2] = bv;
    ta.out[2] = vb; ta.scale[2] = 1.0f;
    gemm_qkv_kernel<<<dim3(768), dim3(256), 0, stream>>>(ta);

    attn_mfma_kernel<<<dim3(512), dim3(512), 0, stream>>>(qb, kb, vb, ctx);

    gemm_out_kernel<<<dim3(8, 32), dim3(256), 0, stream>>>(
        (const short*)ctx, (const short*)wob, bo, out);
}